// Round 2
// baseline (591.188 us; speedup 1.0000x reference)
//
#include <hip/hip_runtime.h>
#include <stdint.h>

#define N_ROWS 16384
#define K_DIM  2048
#define N_OUT  2048
#define NGROUPS 8
#define BM 256
#define BN 256
#define BK 32
#define NT 64        // K_DIM / BK
#define MAX_Y 72     // sum ceil(n_g/256) <= 16384/256 + 8

typedef short s16x8 __attribute__((ext_vector_type(8)));   // 8 bf16 bit-patterns
typedef unsigned short u16x8 __attribute__((ext_vector_type(8)));
typedef float f32x4 __attribute__((ext_vector_type(4)));

// RNE float -> bf16 (bit-level)
__device__ __forceinline__ unsigned short f2bf(float f) {
    unsigned int u = __float_as_uint(f);
    u += 0x7fffu + ((u >> 16) & 1u);
    return (unsigned short)(u >> 16);
}

__global__ void convert_kernel(const float* __restrict__ src,
                               unsigned short* __restrict__ dst, int n) {
    int stride = gridDim.x * blockDim.x;
    for (int i = blockIdx.x * blockDim.x + threadIdx.x; i * 8 < n; i += stride) {
        float4 v0 = *(const float4*)(src + (size_t)i * 8);
        float4 v1 = *(const float4*)(src + (size_t)i * 8 + 4);
        u16x8 o;
        o[0] = f2bf(v0.x); o[1] = f2bf(v0.y); o[2] = f2bf(v0.z); o[3] = f2bf(v0.w);
        o[4] = f2bf(v1.x); o[5] = f2bf(v1.y); o[6] = f2bf(v1.z); o[7] = f2bf(v1.w);
        *(u16x8*)(dst + (size_t)i * 8) = o;
    }
}

__device__ __forceinline__ int lower_bound_g(const int* __restrict__ gi, int g) {
    int lo = 0, hi = N_ROWS;
    while (lo < hi) { int mid = (lo + hi) >> 1; if (gi[mid] < g) lo = mid + 1; else hi = mid; }
    return lo;
}

#define GLDS16(gp, lp) \
    __builtin_amdgcn_global_load_lds((__attribute__((address_space(1))) void*)(gp), \
                                     (__attribute__((address_space(3))) void*)(lp), 16, 0, 0)

#define BAR()   asm volatile("s_barrier" ::: "memory")
#define LGKM6() do { asm volatile("s_waitcnt lgkmcnt(6)" ::: "memory"); \
                     __builtin_amdgcn_sched_barrier(0); } while (0)
#define VMW2()  asm volatile("s_waitcnt vmcnt(2)" ::: "memory")
#define KEEP(x) asm volatile("" :: "v"(x))

// ---------------------------------------------------------------------------
// 256x256xBK32, 8 waves (2Mx4N, 128x64 per wave), 3-buffer LDS ring.
// Software-pipelined phases: reads issued one phase ahead (counted lgkmcnt(6)),
// staging 2 gload_lds/phase with counted vmcnt(2) — neither counter ever
// drains to 0 in the main loop. One s_barrier per phase.
// LDS: A = 3 x [256 rows x 32k] (16KB regions) at 0; B same at +49152.
// Swizzle: 16B slot ^= (row>>1)&3, inverse on global source (rule #21).
// ---------------------------------------------------------------------------
__global__ __launch_bounds__(512, 2) void grouped_gemm(
    const unsigned short* __restrict__ xb,   // [N, K] bf16
    const unsigned short* __restrict__ wb,   // [G, N_OUT, K] bf16
    const float* __restrict__ bias,          // [G, N_OUT] fp32
    const int* __restrict__ gi,              // sorted [N]
    float* __restrict__ out)                 // [N, N_OUT] fp32
{
    __shared__ unsigned char lds[98304];
    __shared__ int sh_s[NGROUPS + 1];

    const int t = threadIdx.x;

    if (t <= NGROUPS)
        sh_s[t] = (t == 0) ? 0 : (t == NGROUPS ? N_ROWS : lower_bound_g(gi, t));
    __syncthreads();

    int by = blockIdx.y;
    int row0 = -1, g = 0, nrows = 0, c = 0;
    #pragma unroll
    for (int gg = 0; gg < NGROUPS; gg++) {
        int n = sh_s[gg + 1] - sh_s[gg];
        int tiles = (n + BM - 1) >> 8;
        if (row0 < 0 && by < c + tiles) {
            g = gg;
            row0 = sh_s[gg] + (by - c) * BM;
            nrows = n - (by - c) * BM; if (nrows > BM) nrows = BM;
        }
        c += tiles;
    }
    if (row0 < 0) return;   // uniform early-out (after the only __syncthreads)
    int col0 = blockIdx.x * BN;

    // ---- staging: thread t -> (row = t>>2 [+128 for 2nd instr], 16B slot t&3)
    int rsub = t >> 2;
    int swz  = (t & 3) ^ ((rsub >> 1) & 3);   // inverse swizzle on SOURCE slot
    int ar0 = min(row0 + rsub,       N_ROWS - 1);
    int ar1 = min(row0 + 128 + rsub, N_ROWS - 1);
    const unsigned short* srcA0 = xb + (size_t)ar0 * K_DIM + swz * 8;
    const unsigned short* srcA1 = xb + (size_t)ar1 * K_DIM + swz * 8;
    const unsigned short* srcB0 = wb + ((size_t)g * N_OUT + col0 + rsub) * K_DIM + swz * 8;
    const unsigned short* srcB1 = srcB0 + (size_t)128 * K_DIM;
    char* dA = (char*)lds + t * 16;
    char* dB = (char*)lds + 49152 + t * 16;

#define STG_A(OFF, KT) do { \
    GLDS16(srcA0 + (KT) * 32, dA + (OFF)); \
    GLDS16(srcA1 + (KT) * 32, dA + (OFF) + 8192); } while (0)
#define STG_B(OFF, KT) do { \
    GLDS16(srcB0 + (KT) * 32, dB + (OFF)); \
    GLDS16(srcB1 + (KT) * 32, dB + (OFF) + 8192); } while (0)

    // ---- fragment reads (wave layout 2M x 4N) ----
    int w = t >> 6, l = t & 63, la = l & 15, q = l >> 4;
    int wm = w >> 2, wn = w & 3;
    // (row>>1)&3 depends only on la bits for our row strides (16/64/128)
    int swr = (q ^ ((la >> 1) & 3)) * 16;
    const char* ldsAr = (const char*)lds;
    const char* ldsBr = (const char*)lds + 49152;
    int aBase = (wm * 128 + la) * 64 + swr;   // + mi*1024 + region
    int bBase = (wn * 64  + la) * 64 + swr;   // + ni*1024 + region

#define RDA(DST, OFF, MI) DST = *(const s16x8*)(ldsAr + (OFF) + aBase + (MI) * 1024)
#define RDB(DST, OFF, NI) DST = *(const s16x8*)(ldsBr + (OFF) + bBase + (NI) * 1024)

    f32x4 acc[8][4];
    #pragma unroll
    for (int i2 = 0; i2 < 8; i2++)
        #pragma unroll
        for (int j2 = 0; j2 < 4; j2++)
            acc[i2][j2] = (f32x4){0.f, 0.f, 0.f, 0.f};

    s16x8 aE[8], aO[8], bE[4], bO[4];
    int oA0 = 0, oA1 = 16384, oA2 = 32768;   // regions for tiles t, t+1, t+2
    int oB0 = 0, oB1 = 16384, oB2 = 32768;

#define MF2(AC, BL, BH, N0, N1) do { \
    __builtin_amdgcn_s_setprio(1); \
    _Pragma("unroll") for (int mi = 0; mi < 8; mi++) { \
        acc[mi][N0] = __builtin_amdgcn_mfma_f32_16x16x32_bf16(AC[mi], BL, acc[mi][N0], 0, 0, 0); \
        acc[mi][N1] = __builtin_amdgcn_mfma_f32_16x16x32_bf16(AC[mi], BH, acc[mi][N1], 0, 0, 0); } \
    __builtin_amdgcn_s_setprio(0); } while (0)

// One K-tile (t) = 2 phases. Reads are one phase ahead of their MFMA use;
// lgkmcnt(6) waits only for the PREVIOUS phase's 6 reads; vmcnt(2) keeps the
// 1-phase-old staging pair in flight and drains the 2-phase-old pair.
// Staging targets regions disjoint from all in-flight reads (ledger-verified).
#define TILE(AC, AN, BC, BN_, OA1_, OB0_, OB1_, OB2S, OA0S, KB, KA) do { \
    /* PA: issue b_t[2,3] + a_{t+1}[0..3]; MFMA a_t x b_t[0,1] */ \
    RDB(BC[2], OB0_, 2); RDB(BC[3], OB0_, 3); \
    RDA(AN[0], OA1_, 0); RDA(AN[1], OA1_, 1); RDA(AN[2], OA1_, 2); RDA(AN[3], OA1_, 3); \
    LGKM6(); \
    MF2(AC, BC[0], BC[1], 0, 1); \
    VMW2(); BAR(); \
    STG_B(OB2S, KB); \
    /* PB: issue a_{t+1}[4..7] + b_{t+1}[0,1]; MFMA a_t x b_t[2,3] */ \
    RDA(AN[4], OA1_, 4); RDA(AN[5], OA1_, 5); RDA(AN[6], OA1_, 6); RDA(AN[7], OA1_, 7); \
    RDB(BN_[0], OB1_, 0); RDB(BN_[1], OB1_, 1); \
    LGKM6(); \
    MF2(AC, BC[2], BC[3], 2, 3); \
    VMW2(); BAR(); \
    STG_A(OA0S, KA); \
} while (0)

    // Prologue: stage A0,B0,A1 (these must land) then B1,A2 (stay in flight).
    STG_A(oA0, 0); STG_B(oB0, 0); STG_A(oA1, 1);
    STG_B(oB1, 1); STG_A(oA2, 2);
    asm volatile("s_waitcnt vmcnt(4)" ::: "memory");
    BAR();
    // Pre-reads emulating PA(-1)/PB(-1): a_0[0..7], b_0[0,1]
    RDA(aE[0], oA0, 0); RDA(aE[1], oA0, 1); RDA(aE[2], oA0, 2); RDA(aE[3], oA0, 3);
    RDA(aE[4], oA0, 4); RDA(aE[5], oA0, 5); RDA(aE[6], oA0, 6); RDA(aE[7], oA0, 7);
    RDB(bE[0], oB0, 0); RDB(bE[1], oB0, 1);

    #pragma unroll 1
    for (int i = 0; i < NT / 2; i++) {
        int tE = 2 * i;
        int kB0 = min(tE + 2, NT - 1), kA0 = min(tE + 3, NT - 1);
        int kB1 = min(tE + 3, NT - 1), kA1 = min(tE + 4, NT - 1);
        TILE(aE, aO, bE, bO, oA1, oB0, oB1, oB2, oA0, kB0, kA0);
        int tmp = oA0; oA0 = oA1; oA1 = oA2; oA2 = tmp;
        tmp = oB0; oB0 = oB1; oB1 = oB2; oB2 = tmp;
        TILE(aO, aE, bO, bE, oA1, oB0, oB1, oB2, oA0, kB1, kA1);
        tmp = oA0; oA0 = oA1; oA1 = oA2; oA2 = tmp;
        tmp = oB0; oB0 = oB1; oB1 = oB2; oB2 = tmp;
    }
    asm volatile("s_waitcnt vmcnt(0)" ::: "memory");
    __builtin_amdgcn_sched_barrier(0);

    // Keep the final (dead) prefetch reads alive so DCE can't change the
    // lgkmcnt(6) accounting inside the loop (rule #17).
    #pragma unroll
    for (int i2 = 0; i2 < 8; i2++) { KEEP(aE[i2]); KEEP(aO[i2]); }
    #pragma unroll
    for (int i2 = 0; i2 < 4; i2++) { KEEP(bE[i2]); KEEP(bO[i2]); }

    // Epilogue: C/D layout col=lane&15, row=quad*4+reg (m89/m91-verified); fused bias.
    int row_end = row0 + nrows;
    float bv[4];
    #pragma unroll
    for (int ni = 0; ni < 4; ni++)
        bv[ni] = bias[g * N_OUT + col0 + wn * 64 + ni * 16 + la];
    #pragma unroll
    for (int mi = 0; mi < 8; mi++) {
        int rbase = row0 + wm * 128 + mi * 16 + q * 4;
        #pragma unroll
        for (int r = 0; r < 4; r++) {
            int row = rbase + r;
            if (row < row_end) {
                float* op = out + (size_t)row * N_OUT + col0 + wn * 64 + la;
                #pragma unroll
                for (int ni = 0; ni < 4; ni++)
                    op[ni * 16] = acc[mi][ni][r] + bv[ni];
            }
        }
    }
}

// Last-resort fallback (ws too small for bf16 copies): correct fp32 path.
__global__ void naive_kernel(const float* __restrict__ x, const float* __restrict__ wgt,
                             const float* __restrict__ bias, const int* __restrict__ gi,
                             float* __restrict__ out) {
    int row = blockIdx.x;
    int g = gi[row] & (NGROUPS - 1);
    __shared__ float xs[K_DIM];
    for (int i = threadIdx.x; i < K_DIM; i += 256) xs[i] = x[(size_t)row * K_DIM + i];
    __syncthreads();
    for (int c = threadIdx.x; c < N_OUT; c += 256) {
        const float* wr = wgt + ((size_t)g * N_OUT + c) * K_DIM;
        float s = 0.f;
        for (int k = 0; k < K_DIM; k++) s += xs[k] * wr[k];
        out[(size_t)row * N_OUT + c] = s + bias[g * N_OUT + c];
    }
}

extern "C" void kernel_launch(void* const* d_in, const int* in_sizes, int n_in,
                              void* d_out, int out_size, void* d_ws, size_t ws_size,
                              hipStream_t stream) {
    const float* x    = (const float*)d_in[0];
    const float* wgt  = (const float*)d_in[1];
    const float* bias = (const float*)d_in[2];
    const int*   gi   = (const int*)d_in[3];
    float* out = (float*)d_out;

    const size_t xb_bytes = (size_t)N_ROWS * K_DIM * 2;           // 64 MiB
    const size_t wb_bytes = (size_t)NGROUPS * N_OUT * K_DIM * 2;  // 64 MiB
    const size_t need = xb_bytes + wb_bytes;                      // exactly 128 MiB

    if (ws_size < need) {
        naive_kernel<<<dim3(N_ROWS), dim3(256), 0, stream>>>(x, wgt, bias, gi, out);
        return;
    }

    unsigned short* xb = (unsigned short*)d_ws;
    unsigned short* wb = (unsigned short*)((char*)d_ws + xb_bytes);

    convert_kernel<<<dim3(8192), dim3(256), 0, stream>>>(x,   xb, N_ROWS * K_DIM);
    convert_kernel<<<dim3(8192), dim3(256), 0, stream>>>(wgt, wb, NGROUPS * N_OUT * K_DIM);
    grouped_gemm<<<dim3(N_OUT / BN, MAX_Y), dim3(512), 0, stream>>>(
        xb, wb, bias, gi, out);
}